// Round 9
// baseline (219.745 us; speedup 1.0000x reference)
//
#include <hip/hip_runtime.h>

// B=2, S=2048, D=1024, H=16, DK=DV=64. M = B*S = 4096.
// Reference reshape (B,S,H*DK)->(B,H,S,DK) is a raw reinterpret: chunk
// c = flat>>17 is "head" c, viewed as [2048][64].
//
// SESSION FINDINGS:
//  - __builtin_amdgcn_exp2f gave absmax~0.72 in two structures (R3,R6);
//    __expf passes (R4,R5,R7). Do not use the exp2 builtin. (cp16 was
//    exonerated by the R6/R7 bisection: exp2 alone reproduced the failure.)
//  - Q pre-scaled by 0.125f (exact pow2) in QKV epilogue.
//  - PV via 16x16x16 MFMA regressed (R8): K=16 burns same issue slots as
//    K=32 for half the work. Keep K=32 + P LDS round-trip.

typedef __attribute__((ext_vector_type(8))) __bf16 bf16x8;
typedef __attribute__((ext_vector_type(8))) unsigned short ushort8;
typedef __attribute__((ext_vector_type(4))) float f32x4;

static __device__ __forceinline__ unsigned short f2bf(float f) {
    unsigned u = __builtin_bit_cast(unsigned, f);
    u += 0x7fffu + ((u >> 16) & 1u);
    return (unsigned short)(u >> 16);
}

static __device__ __forceinline__ void cp16(void* lds, const void* g) {
    __builtin_amdgcn_global_load_lds(
        (const __attribute__((address_space(1))) unsigned int*)g,
        (__attribute__((address_space(3))) unsigned int*)lds, 16, 0, 0);
}

__global__ __launch_bounds__(256) void cast_kernel(const float* __restrict__ src,
                                                   unsigned short* __restrict__ dst, int n4) {
    int i = blockIdx.x * 256 + threadIdx.x;
    if (i >= n4) return;
    float4 v = ((const float4*)src)[i];
    ushort4 o;
    o.x = f2bf(v.x); o.y = f2bf(v.y); o.z = f2bf(v.z); o.w = f2bf(v.w);
    ((ushort4*)dst)[i] = o;
}

// Transpose+cast one 1024x1024 fp32 weight [k][n] -> bf16 [n][k].
__global__ __launch_bounds__(256) void castT_kernel(const float* __restrict__ src,
                                                    unsigned short* __restrict__ dst) {
    __shared__ __align__(16) unsigned short t[64 * 68];
    const int tid = threadIdx.x;
    const int n0 = blockIdx.x * 64, k0 = blockIdx.y * 64;
    #pragma unroll
    for (int u = 0; u < 4; u++) {
        int e = u * 256 + tid;
        int r = e >> 4, c4 = (e & 15) * 4;
        float4 v = *(const float4*)(src + (k0 + r) * 1024 + n0 + c4);
        ushort4 o;
        o.x = f2bf(v.x); o.y = f2bf(v.y); o.z = f2bf(v.z); o.w = f2bf(v.w);
        *(ushort4*)(t + r * 68 + c4) = o;
    }
    __syncthreads();
    #pragma unroll
    for (int u = 0; u < 4; u++) {
        int e = u * 256 + tid;
        int rn = e >> 4, ck = (e & 15) * 4;
        ushort4 o;
        o.x = t[(ck + 0) * 68 + rn];
        o.y = t[(ck + 1) * 68 + rn];
        o.z = t[(ck + 2) * 68 + rn];
        o.w = t[(ck + 3) * 68 + rn];
        *(ushort4*)(dst + (n0 + rn) * 1024 + k0 + ck) = o;
    }
}

// Transpose bf16 V-projection [4096][1024] into per-chunk VT[ch][dv][pos].
__global__ __launch_bounds__(256) void vtrans_kernel(const unsigned short* __restrict__ V,
                                                     unsigned short* __restrict__ VT) {
    __shared__ __align__(16) unsigned short t[64 * 68];
    const int tid = threadIdx.x;
    const int p0 = blockIdx.x * 64;
    const long base = (long)blockIdx.y * 131072;
    #pragma unroll
    for (int u = 0; u < 2; u++) {
        int e = u * 256 + tid;
        int r = e >> 3, c8 = (e & 7) * 8;
        ushort8 v = *(const ushort8*)(V + base + (long)(p0 + r) * 64 + c8);
        *(ushort8*)(t + r * 68 + c8) = v;
    }
    __syncthreads();
    #pragma unroll
    for (int u = 0; u < 4; u++) {
        int e = u * 256 + tid;
        int dv = e >> 4, pk = (e & 15) * 4;
        ushort4 o;
        o.x = t[(pk + 0) * 68 + dv];
        o.y = t[(pk + 1) * 68 + dv];
        o.z = t[(pk + 2) * 68 + dv];
        o.w = t[(pk + 3) * 68 + dv];
        *(ushort4*)(VT + base + (long)dv * 2048 + p0 + pk) = o;
    }
}

// 128x128-tile GEMM, BK=32, 4 waves (2x2). m97-style global_load_lds (16B)
// staging + double-buffered LDS, ONE barrier per K-iteration: cp16 of tile
// k+1 is in flight across the ds_read+MFMA of tile k.
// mode 0 (QKV, N=3072): which = n0g>>10 selects outQ/outK/outV; Q scaled 0.125.
// mode 1 (out-proj, N=1024): out = acc + bias + resid, fp32.
__global__ __launch_bounds__(256, 3) void gemm_kernel(
    const unsigned short* __restrict__ A,
    const unsigned short* __restrict__ Bt,
    const float* __restrict__ b0, const float* __restrict__ b1, const float* __restrict__ b2,
    unsigned short* __restrict__ outQ, unsigned short* __restrict__ outK,
    unsigned short* __restrict__ outV,
    float* __restrict__ outF, const float* __restrict__ resid, int mode)
{
    __shared__ __align__(16) unsigned short As[2][128 * 32];
    __shared__ __align__(16) unsigned short Bs[2][128 * 32];
    const int tid = threadIdx.x;
    const int lane = tid & 63, wave = tid >> 6;
    const int quad = lane >> 4, l16 = lane & 15;
    const int wm = wave >> 1, wn = wave & 1;
    const int row0 = blockIdx.y * 128, n0g = blockIdx.x * 128;

    // lane l of wave w stages row (w*16 + l>>2), k-bytes (l&3)*16:
    // LDS dest = wave-uniform base + l*16  (matches [m][k] stride-32 layout)
    const unsigned short* Ag = A + (size_t)(row0 + wave * 16 + (lane >> 2)) * 1024 + (lane & 3) * 8;
    const unsigned short* Bg = Bt + (size_t)(n0g + wave * 16 + (lane >> 2)) * 1024 + (lane & 3) * 8;
    char* AsP[2] = { (char*)As[0] + wave * 1024, (char*)As[1] + wave * 1024 };
    char* BsP[2] = { (char*)Bs[0] + wave * 1024, (char*)Bs[1] + wave * 1024 };

    cp16(AsP[0],        Ag);
    cp16(AsP[0] + 4096, Ag + 64 * 1024);
    cp16(BsP[0],        Bg);
    cp16(BsP[0] + 4096, Bg + 64 * 1024);
    __syncthreads();

    f32x4 acc[4][4] = {};
    #pragma unroll 2
    for (int it = 0; it < 32; ++it) {
        const int cur = it & 1;
        if (it < 31) {
            const int k0 = (it + 1) * 32;
            const int nxt = cur ^ 1;
            cp16(AsP[nxt],        Ag + k0);
            cp16(AsP[nxt] + 4096, Ag + 64 * 1024 + k0);
            cp16(BsP[nxt],        Bg + k0);
            cp16(BsP[nxt] + 4096, Bg + 64 * 1024 + k0);
        }
        bf16x8 af[4], bfr[4];
        #pragma unroll
        for (int i = 0; i < 4; i++)
            af[i] = *(const bf16x8*)(As[cur] + (wm * 64 + i * 16 + l16) * 32 + quad * 8);
        #pragma unroll
        for (int j = 0; j < 4; j++)
            bfr[j] = *(const bf16x8*)(Bs[cur] + (wn * 64 + j * 16 + l16) * 32 + quad * 8);
        #pragma unroll
        for (int i = 0; i < 4; i++)
            #pragma unroll
            for (int j = 0; j < 4; j++)
                acc[i][j] = __builtin_amdgcn_mfma_f32_16x16x32_bf16(af[i], bfr[j], acc[i][j], 0, 0, 0);
        if (it < 31) __syncthreads();
    }

    if (mode == 0) {
        const int which = n0g >> 10;
        const float* bp = (which == 0) ? b0 : (which == 1) ? b1 : b2;
        unsigned short* op = (which == 0) ? outQ : (which == 1) ? outK : outV;
        const float scl = (which == 0) ? 0.125f : 1.0f;
        #pragma unroll
        for (int i = 0; i < 4; i++)
            #pragma unroll
            for (int j = 0; j < 4; j++) {
                int c = (n0g + wn * 64 + j * 16 + l16) & 1023;
                float bj = bp[c];
                #pragma unroll
                for (int r = 0; r < 4; r++) {
                    int r_g = row0 + wm * 64 + i * 16 + quad * 4 + r;
                    op[(size_t)r_g * 1024 + c] = f2bf((acc[i][j][r] + bj) * scl);
                }
            }
    } else {
        #pragma unroll
        for (int i = 0; i < 4; i++)
            #pragma unroll
            for (int j = 0; j < 4; j++) {
                int c_g = n0g + wn * 64 + j * 16 + l16;
                float bj = b0[c_g];
                #pragma unroll
                for (int r = 0; r < 4; r++) {
                    int r_g = row0 + wm * 64 + i * 16 + quad * 4 + r;
                    size_t idx = (size_t)r_g * 1024 + c_g;
                    outF[idx] = acc[i][j][r] + bj + resid[idx];
                }
            }
    }
}

// Causal flash attention per chunk (R7-proven version). Grid (32 bh, 32 qy);
// qb = 31-qy (LPT). Block 256 = 4 waves x 16 q-rows; k-tile 128; register
// prefetch of next K/V tile; no-max softmax (Q pre-scaled; p = __expf(s)).
__global__ __launch_bounds__(256, 3) void flash_kernel(
    const unsigned short* __restrict__ Q,
    const unsigned short* __restrict__ K,
    const unsigned short* __restrict__ VT,
    unsigned short* __restrict__ Ctx)
{
    __shared__ __align__(16) unsigned short Kt[128 * 72];    // [kpos][dk]
    __shared__ __align__(16) unsigned short Vt[64 * 136];    // [dv][kpos]
    __shared__ __align__(16) unsigned short Pt[4][16 * 140]; // per-wave [m][kpos]
    const int tid = threadIdx.x;
    const int lane = tid & 63, wave = tid >> 6;
    const int quad = lane >> 4, l16 = lane & 15;
    const int qb = 31 - blockIdx.y;
    const int q0 = qb * 64;
    const long base = (long)blockIdx.x * 131072;

    bf16x8 qa[2];
    #pragma unroll
    for (int kk = 0; kk < 2; kk++)
        qa[kk] = *(const bf16x8*)(Q + base + (q0 + wave * 16 + l16) * 64 + kk * 32 + quad * 8);

    f32x4 o[4] = {};
    float l_part[4] = {0.f, 0.f, 0.f, 0.f};
    const int nt = (qb + 2) >> 1;

    #pragma unroll
    for (int u = 0; u < 4; u++) {
        int e = u * 256 + tid;
        int r = e >> 3, c = (e & 7) * 8;
        *(ushort8*)(Kt + r * 72 + c) = *(const ushort8*)(K + base + (long)r * 64 + c);
        int dv = e >> 4, kc = (e & 15) * 8;
        *(ushort8*)(Vt + dv * 136 + kc) = *(const ushort8*)(VT + base + (long)dv * 2048 + kc);
    }
    __syncthreads();

    for (int t = 0; t < nt; t++) {
        ushort8 nk[4], nv[4];
        if (t + 1 < nt) {
            const int k1 = (t + 1) * 128;
            #pragma unroll
            for (int u = 0; u < 4; u++) {
                int e = u * 256 + tid;
                int r = e >> 3, c = (e & 7) * 8;
                nk[u] = *(const ushort8*)(K + base + (long)(k1 + r) * 64 + c);
                int dv = e >> 4, kc = (e & 15) * 8;
                nv[u] = *(const ushort8*)(VT + base + (long)dv * 2048 + k1 + kc);
            }
        }
        const int k0 = t * 128;

        f32x4 s[8];
        #pragma unroll
        for (int c = 0; c < 8; c++) {
            bf16x8 kb0 = *(const bf16x8*)(Kt + (c * 16 + l16) * 72 + quad * 8);
            bf16x8 kb1 = *(const bf16x8*)(Kt + (c * 16 + l16) * 72 + 32 + quad * 8);
            f32x4 a = {};
            a = __builtin_amdgcn_mfma_f32_16x16x32_bf16(qa[0], kb0, a, 0, 0, 0);
            a = __builtin_amdgcn_mfma_f32_16x16x32_bf16(qa[1], kb1, a, 0, 0, 0);
            s[c] = a;
        }
        const bool diag = (t == nt - 1);
        #pragma unroll
        for (int c = 0; c < 8; c++)
            #pragma unroll
            for (int r = 0; r < 4; r++) {
                float p = __expf(s[c][r]);   // Q pre-scaled by 1/8
                if (diag) {
                    int kpos = k0 + c * 16 + l16;
                    int qpos = q0 + wave * 16 + quad * 4 + r;
                    p = (kpos > qpos) ? 0.f : p;
                }
                s[c][r] = p;
            }
        #pragma unroll
        for (int r = 0; r < 4; r++) {
            float t0 = (s[0][r] + s[1][r]) + (s[2][r] + s[3][r]);
            float t1 = (s[4][r] + s[5][r]) + (s[6][r] + s[7][r]);
            l_part[r] += t0 + t1;
        }
        unsigned short* pw = Pt[wave];
        #pragma unroll
        for (int c = 0; c < 8; c++)
            #pragma unroll
            for (int r = 0; r < 4; r++)
                pw[(quad * 4 + r) * 140 + c * 16 + l16] = f2bf(s[c][r]);
        bf16x8 pa[4];
        #pragma unroll
        for (int kk = 0; kk < 4; kk++) {
            const unsigned short* pr = pw + l16 * 140 + kk * 32 + quad * 8;
            ushort4 lo = *(const ushort4*)(pr);
            ushort4 hi = *(const ushort4*)(pr + 4);
            ushort8 u8;
            u8[0] = lo.x; u8[1] = lo.y; u8[2] = lo.z; u8[3] = lo.w;
            u8[4] = hi.x; u8[5] = hi.y; u8[6] = hi.z; u8[7] = hi.w;
            pa[kk] = __builtin_bit_cast(bf16x8, u8);
        }
        #pragma unroll
        for (int c2 = 0; c2 < 4; c2++)
            #pragma unroll
            for (int kk = 0; kk < 4; kk++) {
                bf16x8 vb = *(const bf16x8*)(Vt + (c2 * 16 + l16) * 136 + kk * 32 + quad * 8);
                o[c2] = __builtin_amdgcn_mfma_f32_16x16x32_bf16(pa[kk], vb, o[c2], 0, 0, 0);
            }
        __syncthreads();
        if (t + 1 < nt) {
            #pragma unroll
            for (int u = 0; u < 4; u++) {
                int e = u * 256 + tid;
                int r = e >> 3, c = (e & 7) * 8;
                *(ushort8*)(Kt + r * 72 + c) = nk[u];
                int dv = e >> 4, kc = (e & 15) * 8;
                *(ushort8*)(Vt + dv * 136 + kc) = nv[u];
            }
            __syncthreads();
        }
    }

    #pragma unroll
    for (int r = 0; r < 4; r++) {
        float l = l_part[r];
        #pragma unroll
        for (int off = 1; off < 16; off <<= 1) l += __shfl_xor(l, off, 64);
        l_part[r] = 1.0f / l;
    }
    #pragma unroll
    for (int c2 = 0; c2 < 4; c2++)
        #pragma unroll
        for (int r = 0; r < 4; r++) {
            int row = q0 + wave * 16 + quad * 4 + r;
            Ctx[base + (long)row * 64 + c2 * 16 + l16] = f2bf(o[c2][r] * l_part[r]);
        }
}

__global__ __launch_bounds__(256) void ln_kernel(const float* __restrict__ inp,
                                                 const float* __restrict__ gamma,
                                                 const float* __restrict__ beta,
                                                 float* __restrict__ out)
{
    __shared__ float ssum[4], ssq[4];
    const int row = blockIdx.x;
    const int tid = threadIdx.x;
    float4 v = ((const float4*)(inp + (size_t)row * 1024))[tid];
    float s = v.x + v.y + v.z + v.w;
    float q = v.x * v.x + v.y * v.y + v.z * v.z + v.w * v.w;
    #pragma unroll
    for (int off = 32; off >= 1; off >>= 1) {
        s += __shfl_xor(s, off, 64);
        q += __shfl_xor(q, off, 64);
    }
    if ((tid & 63) == 0) { ssum[tid >> 6] = s; ssq[tid >> 6] = q; }
    __syncthreads();
    float ts = ssum[0] + ssum[1] + ssum[2] + ssum[3];
    float tq = ssq[0] + ssq[1] + ssq[2] + ssq[3];
    float mean = ts * (1.f / 1024.f);
    float var = tq * (1.f / 1024.f) - mean * mean;
    float rinv = rsqrtf(var + 1e-5f);
    float4 g = ((const float4*)gamma)[tid];
    float4 b = ((const float4*)beta)[tid];
    float4 o;
    o.x = (v.x - mean) * rinv * g.x + b.x;
    o.y = (v.y - mean) * rinv * g.y + b.y;
    o.z = (v.z - mean) * rinv * g.z + b.z;
    o.w = (v.w - mean) * rinv * g.w + b.w;
    ((float4*)(out + (size_t)row * 1024))[tid] = o;
}

extern "C" void kernel_launch(void* const* d_in, const int* in_sizes, int n_in,
                              void* d_out, int out_size, void* d_ws, size_t ws_size,
                              hipStream_t stream) {
    const float* x     = (const float*)d_in[0];
    const float* Wk    = (const float*)d_in[1];
    const float* bk    = (const float*)d_in[2];
    const float* Wq    = (const float*)d_in[3];
    const float* bq    = (const float*)d_in[4];
    const float* Wv    = (const float*)d_in[5];
    const float* bv    = (const float*)d_in[6];
    const float* Wo    = (const float*)d_in[7];
    const float* bo    = (const float*)d_in[8];
    const float* gamma = (const float*)d_in[9];
    const float* beta  = (const float*)d_in[10];
    float* out = (float*)d_out;

    char* ws = (char*)d_ws;
    unsigned short* xb    = (unsigned short*)(ws);                 // 8 MB
    unsigned short* WqkvT = (unsigned short*)(ws + (8ull << 20));  // 6 MB
    unsigned short* WoT   = (unsigned short*)(ws + (14ull << 20)); // 2 MB
    unsigned short* Qb    = (unsigned short*)(ws + (16ull << 20)); // 8 MB
    unsigned short* Kb    = (unsigned short*)(ws + (24ull << 20)); // 8 MB
    unsigned short* VbT   = (unsigned short*)(ws + (32ull << 20)); // 8 MB
    unsigned short* Cb    = (unsigned short*)(ws + (40ull << 20)); // 8 MB
    float* outp           = (float*)(ws + (48ull << 20));          // 16 MB
    unsigned short* Vbn   = Cb;  // V normal layout, dead before flash writes Cb

    cast_kernel<<<4096, 256, 0, stream>>>(x, xb, 1048576);
    dim3 tgrid(16, 16);
    castT_kernel<<<tgrid, 256, 0, stream>>>(Wq, WqkvT);
    castT_kernel<<<tgrid, 256, 0, stream>>>(Wk, WqkvT + (1u << 20));
    castT_kernel<<<tgrid, 256, 0, stream>>>(Wv, WqkvT + (2u << 20));
    castT_kernel<<<tgrid, 256, 0, stream>>>(Wo, WoT);

    dim3 qkvgrid(24, 32);
    gemm_kernel<<<qkvgrid, 256, 0, stream>>>(xb, WqkvT, bq, bk, bv,
                                             Qb, Kb, Vbn, nullptr, nullptr, 0);

    dim3 vgrid(32, 32);
    vtrans_kernel<<<vgrid, 256, 0, stream>>>(Vbn, VbT);

    dim3 fgrid(32, 32);
    flash_kernel<<<fgrid, 256, 0, stream>>>(Qb, Kb, VbT, Cb);

    dim3 ogrid(8, 32);
    gemm_kernel<<<ogrid, 256, 0, stream>>>(Cb, WoT, bo, nullptr, nullptr,
                                           nullptr, nullptr, nullptr, outp, x, 1);

    ln_kernel<<<4096, 256, 0, stream>>>(outp, gamma, beta, out);
}

// Round 10
// 208.144 us; speedup vs baseline: 1.0557x; 1.0557x over previous
//
#include <hip/hip_runtime.h>

// B=2, S=2048, D=1024, H=16, DK=DV=64. M = B*S = 4096.
// Reference reshape (B,S,H*DK)->(B,H,S,DK) is a raw reinterpret: chunk
// c = flat>>17 is "head" c, viewed as [2048][64].
//
// SESSION FINDINGS:
//  - __builtin_amdgcn_exp2f gave absmax~0.72 (R3,R6); __expf passes. Banned.
//  - Q pre-scaled by 0.125f (exact pow2) in QKV epilogue.
//  - PV via 16x16x16 MFMA regressed (R8): K=16 burns same issue slots as
//    K=32 for half the work. Use K=32 everywhere.
//  - cp16(global_load_lds)+dbuf GEMM regressed ~10us vs register-prefetch
//    dbuf (R9): compiler drains vmcnt(0) at the barrier, killing the
//    overlap. Register prefetch carries loads across the barrier in VGPRs.
//  - Flash S^T formulation (mfma(A=K,B=Q)): lane holds 4 CONSECUTIVE kpos
//    per q-row -> P stores are 8 ds_write_b64/tile, not 32 ds_write_b16.

typedef __attribute__((ext_vector_type(8))) __bf16 bf16x8;
typedef __attribute__((ext_vector_type(8))) unsigned short ushort8;
typedef __attribute__((ext_vector_type(4))) unsigned short u16x4;
typedef __attribute__((ext_vector_type(4))) float f32x4;

static __device__ __forceinline__ unsigned short f2bf(float f) {
    unsigned u = __builtin_bit_cast(unsigned, f);
    u += 0x7fffu + ((u >> 16) & 1u);
    return (unsigned short)(u >> 16);
}

__global__ __launch_bounds__(256) void cast_kernel(const float* __restrict__ src,
                                                   unsigned short* __restrict__ dst, int n4) {
    int i = blockIdx.x * 256 + threadIdx.x;
    if (i >= n4) return;
    float4 v = ((const float4*)src)[i];
    ushort4 o;
    o.x = f2bf(v.x); o.y = f2bf(v.y); o.z = f2bf(v.z); o.w = f2bf(v.w);
    ((ushort4*)dst)[i] = o;
}

// Transpose+cast one 1024x1024 fp32 weight [k][n] -> bf16 [n][k].
__global__ __launch_bounds__(256) void castT_kernel(const float* __restrict__ src,
                                                    unsigned short* __restrict__ dst) {
    __shared__ __align__(16) unsigned short t[64 * 68];
    const int tid = threadIdx.x;
    const int n0 = blockIdx.x * 64, k0 = blockIdx.y * 64;
    #pragma unroll
    for (int u = 0; u < 4; u++) {
        int e = u * 256 + tid;
        int r = e >> 4, c4 = (e & 15) * 4;
        float4 v = *(const float4*)(src + (k0 + r) * 1024 + n0 + c4);
        ushort4 o;
        o.x = f2bf(v.x); o.y = f2bf(v.y); o.z = f2bf(v.z); o.w = f2bf(v.w);
        *(ushort4*)(t + r * 68 + c4) = o;
    }
    __syncthreads();
    #pragma unroll
    for (int u = 0; u < 4; u++) {
        int e = u * 256 + tid;
        int rn = e >> 4, ck = (e & 15) * 4;
        ushort4 o;
        o.x = t[(ck + 0) * 68 + rn];
        o.y = t[(ck + 1) * 68 + rn];
        o.z = t[(ck + 2) * 68 + rn];
        o.w = t[(ck + 3) * 68 + rn];
        *(ushort4*)(dst + (n0 + rn) * 1024 + k0 + ck) = o;
    }
}

// Transpose bf16 V-projection [4096][1024] into per-chunk VT[ch][dv][pos].
__global__ __launch_bounds__(256) void vtrans_kernel(const unsigned short* __restrict__ V,
                                                     unsigned short* __restrict__ VT) {
    __shared__ __align__(16) unsigned short t[64 * 68];
    const int tid = threadIdx.x;
    const int p0 = blockIdx.x * 64;
    const long base = (long)blockIdx.y * 131072;
    #pragma unroll
    for (int u = 0; u < 2; u++) {
        int e = u * 256 + tid;
        int r = e >> 3, c8 = (e & 7) * 8;
        ushort8 v = *(const ushort8*)(V + base + (long)(p0 + r) * 64 + c8);
        *(ushort8*)(t + r * 68 + c8) = v;
    }
    __syncthreads();
    #pragma unroll
    for (int u = 0; u < 4; u++) {
        int e = u * 256 + tid;
        int dv = e >> 4, pk = (e & 15) * 4;
        ushort4 o;
        o.x = t[(pk + 0) * 68 + dv];
        o.y = t[(pk + 1) * 68 + dv];
        o.z = t[(pk + 2) * 68 + dv];
        o.w = t[(pk + 3) * 68 + dv];
        *(ushort4*)(VT + base + (long)dv * 2048 + p0 + pk) = o;
    }
}

// 128x128-tile GEMM, BK=32, 4 waves (2x2). Software-pipelined register
// prefetch + double-buffered LDS, one barrier per K-iteration (R7-proven).
// mode 0 (QKV, N=3072): which = n0g>>10 selects outQ/outK/outV; Q scaled 0.125.
// mode 1 (out-proj, N=1024): out = acc + bias + resid, fp32.
__global__ __launch_bounds__(256, 3) void gemm_kernel(
    const unsigned short* __restrict__ A,
    const unsigned short* __restrict__ Bt,
    const float* __restrict__ b0, const float* __restrict__ b1, const float* __restrict__ b2,
    unsigned short* __restrict__ outQ, unsigned short* __restrict__ outK,
    unsigned short* __restrict__ outV,
    float* __restrict__ outF, const float* __restrict__ resid, int mode)
{
    __shared__ __align__(16) unsigned short As[2][128 * 32];
    __shared__ __align__(16) unsigned short Bs[2][128 * 32];
    const int tid = threadIdx.x;
    const int lane = tid & 63, wave = tid >> 6;
    const int quad = lane >> 4, l16 = lane & 15;
    const int wm = wave >> 1, wn = wave & 1;
    const int row0 = blockIdx.y * 128, n0g = blockIdx.x * 128;

    const int sr = tid >> 2;
    const int sc = (tid & 3) * 8;
    const unsigned short* Ag0 = A + (size_t)(row0 + sr) * 1024 + sc;
    const unsigned short* Ag1 = A + (size_t)(row0 + 64 + sr) * 1024 + sc;
    const unsigned short* Bg0 = Bt + (size_t)(n0g + sr) * 1024 + sc;
    const unsigned short* Bg1 = Bt + (size_t)(n0g + 64 + sr) * 1024 + sc;

    {
        ushort8 a0 = *(const ushort8*)(Ag0);
        ushort8 a1 = *(const ushort8*)(Ag1);
        ushort8 bv0 = *(const ushort8*)(Bg0);
        ushort8 bv1 = *(const ushort8*)(Bg1);
        *(ushort8*)(As[0] + sr * 32 + sc) = a0;
        *(ushort8*)(As[0] + (64 + sr) * 32 + sc) = a1;
        *(ushort8*)(Bs[0] + sr * 32 + sc) = bv0;
        *(ushort8*)(Bs[0] + (64 + sr) * 32 + sc) = bv1;
    }
    __syncthreads();

    f32x4 acc[4][4] = {};
    #pragma unroll 2
    for (int it = 0; it < 32; ++it) {
        const int cur = it & 1;
        ushort8 na0, na1, nb0, nb1;
        if (it < 31) {
            const int k0 = (it + 1) * 32;
            na0 = *(const ushort8*)(Ag0 + k0);
            na1 = *(const ushort8*)(Ag1 + k0);
            nb0 = *(const ushort8*)(Bg0 + k0);
            nb1 = *(const ushort8*)(Bg1 + k0);
        }
        bf16x8 af[4], bfr[4];
        #pragma unroll
        for (int i = 0; i < 4; i++)
            af[i] = *(const bf16x8*)(As[cur] + (wm * 64 + i * 16 + l16) * 32 + quad * 8);
        #pragma unroll
        for (int j = 0; j < 4; j++)
            bfr[j] = *(const bf16x8*)(Bs[cur] + (wn * 64 + j * 16 + l16) * 32 + quad * 8);
        #pragma unroll
        for (int i = 0; i < 4; i++)
            #pragma unroll
            for (int j = 0; j < 4; j++)
                acc[i][j] = __builtin_amdgcn_mfma_f32_16x16x32_bf16(af[i], bfr[j], acc[i][j], 0, 0, 0);
        if (it < 31) {
            const int nxt = cur ^ 1;
            *(ushort8*)(As[nxt] + sr * 32 + sc) = na0;
            *(ushort8*)(As[nxt] + (64 + sr) * 32 + sc) = na1;
            *(ushort8*)(Bs[nxt] + sr * 32 + sc) = nb0;
            *(ushort8*)(Bs[nxt] + (64 + sr) * 32 + sc) = nb1;
            __syncthreads();
        }
    }

    if (mode == 0) {
        const int which = n0g >> 10;
        const float* bp = (which == 0) ? b0 : (which == 1) ? b1 : b2;
        unsigned short* op = (which == 0) ? outQ : (which == 1) ? outK : outV;
        const float scl = (which == 0) ? 0.125f : 1.0f;
        #pragma unroll
        for (int i = 0; i < 4; i++)
            #pragma unroll
            for (int j = 0; j < 4; j++) {
                int c = (n0g + wn * 64 + j * 16 + l16) & 1023;
                float bj = bp[c];
                #pragma unroll
                for (int r = 0; r < 4; r++) {
                    int r_g = row0 + wm * 64 + i * 16 + quad * 4 + r;
                    op[(size_t)r_g * 1024 + c] = f2bf((acc[i][j][r] + bj) * scl);
                }
            }
    } else {
        #pragma unroll
        for (int i = 0; i < 4; i++)
            #pragma unroll
            for (int j = 0; j < 4; j++) {
                int c_g = n0g + wn * 64 + j * 16 + l16;
                float bj = b0[c_g];
                #pragma unroll
                for (int r = 0; r < 4; r++) {
                    int r_g = row0 + wm * 64 + i * 16 + quad * 4 + r;
                    size_t idx = (size_t)r_g * 1024 + c_g;
                    outF[idx] = acc[i][j][r] + bj + resid[idx];
                }
            }
    }
}

// Causal flash attention, S^T formulation + K=32 PV. Grid (32 bh, 32 qy);
// qb = 31-qy (LPT). Block 256 = 4 waves x 16 q-rows; k-tile 128; register
// prefetch of next K/V tile; no-max softmax (Q pre-scaled; p = __expf(s)).
// S^T = mfma(A=K,B=Q): lane holds q-row l16, kpos quad*4+r (consecutive!)
// -> P stores are 8 ds_write_b64/tile; PV reads A-frags as ds_read_b128.
__global__ __launch_bounds__(256, 3) void flash_kernel(
    const unsigned short* __restrict__ Q,
    const unsigned short* __restrict__ K,
    const unsigned short* __restrict__ VT,
    unsigned short* __restrict__ Ctx)
{
    __shared__ __align__(16) unsigned short Kt[128 * 72];    // [kpos][dk]
    __shared__ __align__(16) unsigned short Vt[64 * 136];    // [dv][kpos]
    __shared__ __align__(16) unsigned short Pt[4][16 * 136]; // per-wave [m][kpos]
    const int tid = threadIdx.x;
    const int lane = tid & 63, wave = tid >> 6;
    const int quad = lane >> 4, l16 = lane & 15;
    const int qb = 31 - blockIdx.y;
    const int q0 = qb * 64;
    const long base = (long)blockIdx.x * 131072;

    bf16x8 qa[2];
    #pragma unroll
    for (int kk = 0; kk < 2; kk++)
        qa[kk] = *(const bf16x8*)(Q + base + (q0 + wave * 16 + l16) * 64 + kk * 32 + quad * 8);

    f32x4 o[4] = {};
    float l_one = 0.f;
    const int nt = (qb + 2) >> 1;
    const int qpos = q0 + wave * 16 + l16;

    #pragma unroll
    for (int u = 0; u < 4; u++) {
        int e = u * 256 + tid;
        int r = e >> 3, c = (e & 7) * 8;
        *(ushort8*)(Kt + r * 72 + c) = *(const ushort8*)(K + base + (long)r * 64 + c);
        int dv = e >> 4, kc = (e & 15) * 8;
        *(ushort8*)(Vt + dv * 136 + kc) = *(const ushort8*)(VT + base + (long)dv * 2048 + kc);
    }
    __syncthreads();

    for (int t = 0; t < nt; t++) {
        ushort8 nk[4], nv[4];
        if (t + 1 < nt) {
            const int k1 = (t + 1) * 128;
            #pragma unroll
            for (int u = 0; u < 4; u++) {
                int e = u * 256 + tid;
                int r = e >> 3, c = (e & 7) * 8;
                nk[u] = *(const ushort8*)(K + base + (long)(k1 + r) * 64 + c);
                int dv = e >> 4, kc = (e & 15) * 8;
                nv[u] = *(const ushort8*)(VT + base + (long)dv * 2048 + k1 + kc);
            }
        }
        const int k0 = t * 128;
        const int climit = (q0 + 63 - k0) >> 4;  // block-uniform; groups c>climit fully masked
        const bool diag = (t == nt - 1);
        unsigned short* pw = Pt[wave];

        #pragma unroll
        for (int c = 0; c < 8; c++) {
            u16x4 pk4 = {};
            if (c <= climit) {
                bf16x8 kb0 = *(const bf16x8*)(Kt + (c * 16 + l16) * 72 + quad * 8);
                bf16x8 kb1 = *(const bf16x8*)(Kt + (c * 16 + l16) * 72 + 32 + quad * 8);
                f32x4 a = {};
                a = __builtin_amdgcn_mfma_f32_16x16x32_bf16(kb0, qa[0], a, 0, 0, 0);
                a = __builtin_amdgcn_mfma_f32_16x16x32_bf16(kb1, qa[1], a, 0, 0, 0);
                // S^T: row quad*4+r = kpos-local, col l16 = q-row
                #pragma unroll
                for (int r = 0; r < 4; r++) {
                    float p = __expf(a[r]);   // Q pre-scaled by 1/8
                    if (diag) {
                        int kpos = k0 + c * 16 + quad * 4 + r;
                        p = (kpos > qpos) ? 0.f : p;
                    }
                    a[r] = p;
                }
                l_one += (a[0] + a[1]) + (a[2] + a[3]);
                pk4[0] = f2bf(a[0]); pk4[1] = f2bf(a[1]);
                pk4[2] = f2bf(a[2]); pk4[3] = f2bf(a[3]);
            }
            *(u16x4*)(pw + l16 * 136 + c * 16 + quad * 4) = pk4;
        }

        const int kkmax = (climit >> 1) < 3 ? (climit >> 1) : 3;
        #pragma unroll
        for (int kk = 0; kk < 4; kk++) {
            if (kk <= kkmax) {
                bf16x8 pa = *(const bf16x8*)(pw + l16 * 136 + kk * 32 + quad * 8);
                #pragma unroll
                for (int c2 = 0; c2 < 4; c2++) {
                    bf16x8 vb = *(const bf16x8*)(Vt + (c2 * 16 + l16) * 136 + kk * 32 + quad * 8);
                    o[c2] = __builtin_amdgcn_mfma_f32_16x16x32_bf16(pa, vb, o[c2], 0, 0, 0);
                }
            }
        }
        __syncthreads();
        if (t + 1 < nt) {
            #pragma unroll
            for (int u = 0; u < 4; u++) {
                int e = u * 256 + tid;
                int r = e >> 3, c = (e & 7) * 8;
                *(ushort8*)(Kt + r * 72 + c) = nk[u];
                int dv = e >> 4, kc = (e & 15) * 8;
                *(ushort8*)(Vt + dv * 136 + kc) = nv[u];
            }
            __syncthreads();
        }
    }

    // l_one: partial row-sum for q-row l16 over this quad's kpos. Reduce quads.
    l_one += __shfl_xor(l_one, 16, 64);
    l_one += __shfl_xor(l_one, 32, 64);
    // O in C-layout: row m = quad*4+r (q-row local), col dv = c2*16+l16.
    float rinv[4];
    #pragma unroll
    for (int r = 0; r < 4; r++)
        rinv[r] = 1.0f / __shfl(l_one, quad * 4 + r, 16);
    #pragma unroll
    for (int c2 = 0; c2 < 4; c2++)
        #pragma unroll
        for (int r = 0; r < 4; r++) {
            int row = q0 + wave * 16 + quad * 4 + r;
            Ctx[base + (long)row * 64 + c2 * 16 + l16] = f2bf(o[c2][r] * rinv[r]);
        }
}

__global__ __launch_bounds__(256) void ln_kernel(const float* __restrict__ inp,
                                                 const float* __restrict__ gamma,
                                                 const float* __restrict__ beta,
                                                 float* __restrict__ out)
{
    __shared__ float ssum[4], ssq[4];
    const int row = blockIdx.x;
    const int tid = threadIdx.x;
    float4 v = ((const float4*)(inp + (size_t)row * 1024))[tid];
    float s = v.x + v.y + v.z + v.w;
    float q = v.x * v.x + v.y * v.y + v.z * v.z + v.w * v.w;
    #pragma unroll
    for (int off = 32; off >= 1; off >>= 1) {
        s += __shfl_xor(s, off, 64);
        q += __shfl_xor(q, off, 64);
    }
    if ((tid & 63) == 0) { ssum[tid >> 6] = s; ssq[tid >> 6] = q; }
    __syncthreads();
    float ts = ssum[0] + ssum[1] + ssum[2] + ssum[3];
    float tq = ssq[0] + ssq[1] + ssq[2] + ssq[3];
    float mean = ts * (1.f / 1024.f);
    float var = tq * (1.f / 1024.f) - mean * mean;
    float rinv = rsqrtf(var + 1e-5f);
    float4 g = ((const float4*)gamma)[tid];
    float4 b = ((const float4*)beta)[tid];
    float4 o;
    o.x = (v.x - mean) * rinv * g.x + b.x;
    o.y = (v.y - mean) * rinv * g.y + b.y;
    o.z = (v.z - mean) * rinv * g.z + b.z;
    o.w = (v.w - mean) * rinv * g.w + b.w;
    ((float4*)(out + (size_t)row * 1024))[tid] = o;
}

extern "C" void kernel_launch(void* const* d_in, const int* in_sizes, int n_in,
                              void* d_out, int out_size, void* d_ws, size_t ws_size,
                              hipStream_t stream) {
    const float* x     = (const float*)d_in[0];
    const float* Wk    = (const float*)d_in[1];
    const float* bk    = (const float*)d_in[2];
    const float* Wq    = (const float*)d_in[3];
    const float* bq    = (const float*)d_in[4];
    const float* Wv    = (const float*)d_in[5];
    const float* bv    = (const float*)d_in[6];
    const float* Wo    = (const float*)d_in[7];
    const float* bo    = (const float*)d_in[8];
    const float* gamma = (const float*)d_in[9];
    const float* beta  = (const float*)d_in[10];
    float* out = (float*)d_out;

    char* ws = (char*)d_ws;
    unsigned short* xb    = (unsigned short*)(ws);                 // 8 MB
    unsigned short* WqkvT = (unsigned short*)(ws + (8ull << 20));  // 6 MB
    unsigned short* WoT   = (unsigned short*)(ws + (14ull << 20)); // 2 MB
    unsigned short* Qb    = (unsigned short*)(ws + (16ull << 20)); // 8 MB
    unsigned short* Kb    = (unsigned short*)(ws + (24ull << 20)); // 8 MB
    unsigned short* VbT   = (unsigned short*)(ws + (32ull << 20)); // 8 MB
    unsigned short* Cb    = (unsigned short*)(ws + (40ull << 20)); // 8 MB
    float* outp           = (float*)(ws + (48ull << 20));          // 16 MB
    unsigned short* Vbn   = Cb;  // V normal layout, dead before flash writes Cb

    cast_kernel<<<4096, 256, 0, stream>>>(x, xb, 1048576);
    dim3 tgrid(16, 16);
    castT_kernel<<<tgrid, 256, 0, stream>>>(Wq, WqkvT);
    castT_kernel<<<tgrid, 256, 0, stream>>>(Wk, WqkvT + (1u << 20));
    castT_kernel<<<tgrid, 256, 0, stream>>>(Wv, WqkvT + (2u << 20));
    castT_kernel<<<tgrid, 256, 0, stream>>>(Wo, WoT);

    dim3 qkvgrid(24, 32);
    gemm_kernel<<<qkvgrid, 256, 0, stream>>>(xb, WqkvT, bq, bk, bv,
                                             Qb, Kb, Vbn, nullptr, nullptr, 0);

    dim3 vgrid(32, 32);
    vtrans_kernel<<<vgrid, 256, 0, stream>>>(Vbn, VbT);

    dim3 fgrid(32, 32);
    flash_kernel<<<fgrid, 256, 0, stream>>>(Qb, Kb, VbT, Cb);

    dim3 ogrid(8, 32);
    gemm_kernel<<<ogrid, 256, 0, stream>>>(Cb, WoT, bo, nullptr, nullptr,
                                           nullptr, nullptr, nullptr, outp, x, 1);

    ln_kernel<<<4096, 256, 0, stream>>>(outp, gamma, beta, out);
}

// Round 11
// 200.247 us; speedup vs baseline: 1.0974x; 1.0394x over previous
//
#include <hip/hip_runtime.h>

// B=2, S=2048, D=1024, H=16, DK=DV=64. M = B*S = 4096.
// Reference reshape (B,S,H*DK)->(B,H,S,DK) is a raw reinterpret: chunk
// c = flat>>17 is "head" c, viewed as [2048][64].
//
// SESSION FINDINGS:
//  - __builtin_amdgcn_exp2f gave absmax~0.72 (R3,R6); __expf passes. Banned.
//  - Q pre-scaled by 0.125f (exact pow2) in QKV epilogue.
//  - PV via 16x16x16 MFMA regressed (R8): K=16 burns same issue slots as
//    K=32 for half the work. Use K=32 everywhere.
//  - cp16+dbuf GEMM regressed vs register-prefetch dbuf (R9): compiler
//    drains vmcnt(0) at the barrier. Register prefetch wins.
//  - Flash S^T (mfma(A=K,B=Q)): P stores as 8 ds_write_b64/tile (R10 win).
//  - ~6-7us per kernel boundary (R10 analysis): fuse small kernels.

typedef __attribute__((ext_vector_type(8))) __bf16 bf16x8;
typedef __attribute__((ext_vector_type(8))) unsigned short ushort8;
typedef __attribute__((ext_vector_type(4))) unsigned short u16x4;
typedef __attribute__((ext_vector_type(4))) float f32x4;

static __device__ __forceinline__ unsigned short f2bf(float f) {
    unsigned u = __builtin_bit_cast(unsigned, f);
    u += 0x7fffu + ((u >> 16) & 1u);
    return (unsigned short)(u >> 16);
}

static __device__ __forceinline__ float bf2f(unsigned short u) {
    return __builtin_bit_cast(float, (unsigned)u << 16);
}

// Fused prep: z<4 -> transpose+cast weight z into WT + z*2^20 ([n][k] bf16);
// z==4 -> cast x slab to bf16. Grid (16,16,5) x 256.
__global__ __launch_bounds__(256) void prep_kernel(
    const float* __restrict__ x,
    const float* __restrict__ Wq, const float* __restrict__ Wk,
    const float* __restrict__ Wv, const float* __restrict__ Wo,
    unsigned short* __restrict__ xb, unsigned short* __restrict__ WT)
{
    const int tid = threadIdx.x;
    const int z = blockIdx.z;
    if (z == 4) {
        const int bid = blockIdx.y * 16 + blockIdx.x;      // 0..255
        const int base = bid * 4096 + tid;
        #pragma unroll
        for (int it = 0; it < 16; it++) {
            int i = base + it * 256;
            float4 v = ((const float4*)x)[i];
            ushort4 o;
            o.x = f2bf(v.x); o.y = f2bf(v.y); o.z = f2bf(v.z); o.w = f2bf(v.w);
            ((ushort4*)xb)[i] = o;
        }
        return;
    }
    const float* src = (z == 0) ? Wq : (z == 1) ? Wk : (z == 2) ? Wv : Wo;
    unsigned short* dst = WT + ((size_t)z << 20);
    __shared__ __align__(16) unsigned short t[64 * 68];
    const int n0 = blockIdx.x * 64, k0 = blockIdx.y * 64;
    #pragma unroll
    for (int u = 0; u < 4; u++) {
        int e = u * 256 + tid;
        int r = e >> 4, c4 = (e & 15) * 4;
        float4 v = *(const float4*)(src + (k0 + r) * 1024 + n0 + c4);
        ushort4 o;
        o.x = f2bf(v.x); o.y = f2bf(v.y); o.z = f2bf(v.z); o.w = f2bf(v.w);
        *(ushort4*)(t + r * 68 + c4) = o;
    }
    __syncthreads();
    #pragma unroll
    for (int u = 0; u < 4; u++) {
        int e = u * 256 + tid;
        int rn = e >> 4, ck = (e & 15) * 4;
        ushort4 o;
        o.x = t[(ck + 0) * 68 + rn];
        o.y = t[(ck + 1) * 68 + rn];
        o.z = t[(ck + 2) * 68 + rn];
        o.w = t[(ck + 3) * 68 + rn];
        *(ushort4*)(dst + (n0 + rn) * 1024 + k0 + ck) = o;
    }
}

// Transpose bf16 V-projection [4096][1024] into per-chunk VT[ch][dv][pos].
__global__ __launch_bounds__(256) void vtrans_kernel(const unsigned short* __restrict__ V,
                                                     unsigned short* __restrict__ VT) {
    __shared__ __align__(16) unsigned short t[64 * 68];
    const int tid = threadIdx.x;
    const int p0 = blockIdx.x * 64;
    const long base = (long)blockIdx.y * 131072;
    #pragma unroll
    for (int u = 0; u < 2; u++) {
        int e = u * 256 + tid;
        int r = e >> 3, c8 = (e & 7) * 8;
        ushort8 v = *(const ushort8*)(V + base + (long)(p0 + r) * 64 + c8);
        *(ushort8*)(t + r * 68 + c8) = v;
    }
    __syncthreads();
    #pragma unroll
    for (int u = 0; u < 4; u++) {
        int e = u * 256 + tid;
        int dv = e >> 4, pk = (e & 15) * 4;
        ushort4 o;
        o.x = t[(pk + 0) * 68 + dv];
        o.y = t[(pk + 1) * 68 + dv];
        o.z = t[(pk + 2) * 68 + dv];
        o.w = t[(pk + 3) * 68 + dv];
        *(ushort4*)(VT + base + (long)dv * 2048 + p0 + pk) = o;
    }
}

// 128x128-tile GEMM, BK=32, 4 waves (2x2). Register-prefetch + dbuf LDS,
// one barrier per K-iteration (R7-proven).
// mode 0 (QKV, N=3072): which = n0g>>10 selects outQ/outK/outV; Q scaled 0.125.
// mode 1 (out-proj, N=1024): outQ = bf16(acc + bias + resid).
__global__ __launch_bounds__(256, 3) void gemm_kernel(
    const unsigned short* __restrict__ A,
    const unsigned short* __restrict__ Bt,
    const float* __restrict__ b0, const float* __restrict__ b1, const float* __restrict__ b2,
    unsigned short* __restrict__ outQ, unsigned short* __restrict__ outK,
    unsigned short* __restrict__ outV,
    const float* __restrict__ resid, int mode)
{
    __shared__ __align__(16) unsigned short As[2][128 * 32];
    __shared__ __align__(16) unsigned short Bs[2][128 * 32];
    const int tid = threadIdx.x;
    const int lane = tid & 63, wave = tid >> 6;
    const int quad = lane >> 4, l16 = lane & 15;
    const int wm = wave >> 1, wn = wave & 1;
    const int row0 = blockIdx.y * 128, n0g = blockIdx.x * 128;

    const int sr = tid >> 2;
    const int sc = (tid & 3) * 8;
    const unsigned short* Ag0 = A + (size_t)(row0 + sr) * 1024 + sc;
    const unsigned short* Ag1 = A + (size_t)(row0 + 64 + sr) * 1024 + sc;
    const unsigned short* Bg0 = Bt + (size_t)(n0g + sr) * 1024 + sc;
    const unsigned short* Bg1 = Bt + (size_t)(n0g + 64 + sr) * 1024 + sc;

    {
        ushort8 a0 = *(const ushort8*)(Ag0);
        ushort8 a1 = *(const ushort8*)(Ag1);
        ushort8 bv0 = *(const ushort8*)(Bg0);
        ushort8 bv1 = *(const ushort8*)(Bg1);
        *(ushort8*)(As[0] + sr * 32 + sc) = a0;
        *(ushort8*)(As[0] + (64 + sr) * 32 + sc) = a1;
        *(ushort8*)(Bs[0] + sr * 32 + sc) = bv0;
        *(ushort8*)(Bs[0] + (64 + sr) * 32 + sc) = bv1;
    }
    __syncthreads();

    f32x4 acc[4][4] = {};
    #pragma unroll 2
    for (int it = 0; it < 32; ++it) {
        const int cur = it & 1;
        ushort8 na0, na1, nb0, nb1;
        if (it < 31) {
            const int k0 = (it + 1) * 32;
            na0 = *(const ushort8*)(Ag0 + k0);
            na1 = *(const ushort8*)(Ag1 + k0);
            nb0 = *(const ushort8*)(Bg0 + k0);
            nb1 = *(const ushort8*)(Bg1 + k0);
        }
        bf16x8 af[4], bfr[4];
        #pragma unroll
        for (int i = 0; i < 4; i++)
            af[i] = *(const bf16x8*)(As[cur] + (wm * 64 + i * 16 + l16) * 32 + quad * 8);
        #pragma unroll
        for (int j = 0; j < 4; j++)
            bfr[j] = *(const bf16x8*)(Bs[cur] + (wn * 64 + j * 16 + l16) * 32 + quad * 8);
        #pragma unroll
        for (int i = 0; i < 4; i++)
            #pragma unroll
            for (int j = 0; j < 4; j++)
                acc[i][j] = __builtin_amdgcn_mfma_f32_16x16x32_bf16(af[i], bfr[j], acc[i][j], 0, 0, 0);
        if (it < 31) {
            const int nxt = cur ^ 1;
            *(ushort8*)(As[nxt] + sr * 32 + sc) = na0;
            *(ushort8*)(As[nxt] + (64 + sr) * 32 + sc) = na1;
            *(ushort8*)(Bs[nxt] + sr * 32 + sc) = nb0;
            *(ushort8*)(Bs[nxt] + (64 + sr) * 32 + sc) = nb1;
            __syncthreads();
        }
    }

    if (mode == 0) {
        const int which = n0g >> 10;
        const float* bp = (which == 0) ? b0 : (which == 1) ? b1 : b2;
        unsigned short* op = (which == 0) ? outQ : (which == 1) ? outK : outV;
        const float scl = (which == 0) ? 0.125f : 1.0f;
        #pragma unroll
        for (int i = 0; i < 4; i++)
            #pragma unroll
            for (int j = 0; j < 4; j++) {
                int c = (n0g + wn * 64 + j * 16 + l16) & 1023;
                float bj = bp[c];
                #pragma unroll
                for (int r = 0; r < 4; r++) {
                    int r_g = row0 + wm * 64 + i * 16 + quad * 4 + r;
                    op[(size_t)r_g * 1024 + c] = f2bf((acc[i][j][r] + bj) * scl);
                }
            }
    } else {
        #pragma unroll
        for (int i = 0; i < 4; i++)
            #pragma unroll
            for (int j = 0; j < 4; j++) {
                int c_g = n0g + wn * 64 + j * 16 + l16;
                float bj = b0[c_g];
                #pragma unroll
                for (int r = 0; r < 4; r++) {
                    int r_g = row0 + wm * 64 + i * 16 + quad * 4 + r;
                    size_t idx = (size_t)r_g * 1024 + c_g;
                    outQ[idx] = f2bf(acc[i][j][r] + bj + resid[idx]);
                }
            }
    }
}

// Causal flash attention, S^T formulation + K=32 PV (R10-proven).
__global__ __launch_bounds__(256, 3) void flash_kernel(
    const unsigned short* __restrict__ Q,
    const unsigned short* __restrict__ K,
    const unsigned short* __restrict__ VT,
    unsigned short* __restrict__ Ctx)
{
    __shared__ __align__(16) unsigned short Kt[128 * 72];    // [kpos][dk]
    __shared__ __align__(16) unsigned short Vt[64 * 136];    // [dv][kpos]
    __shared__ __align__(16) unsigned short Pt[4][16 * 136]; // per-wave [m][kpos]
    const int tid = threadIdx.x;
    const int lane = tid & 63, wave = tid >> 6;
    const int quad = lane >> 4, l16 = lane & 15;
    const int qb = 31 - blockIdx.y;
    const int q0 = qb * 64;
    const long base = (long)blockIdx.x * 131072;

    bf16x8 qa[2];
    #pragma unroll
    for (int kk = 0; kk < 2; kk++)
        qa[kk] = *(const bf16x8*)(Q + base + (q0 + wave * 16 + l16) * 64 + kk * 32 + quad * 8);

    f32x4 o[4] = {};
    float l_one = 0.f;
    const int nt = (qb + 2) >> 1;
    const int qpos = q0 + wave * 16 + l16;

    #pragma unroll
    for (int u = 0; u < 4; u++) {
        int e = u * 256 + tid;
        int r = e >> 3, c = (e & 7) * 8;
        *(ushort8*)(Kt + r * 72 + c) = *(const ushort8*)(K + base + (long)r * 64 + c);
        int dv = e >> 4, kc = (e & 15) * 8;
        *(ushort8*)(Vt + dv * 136 + kc) = *(const ushort8*)(VT + base + (long)dv * 2048 + kc);
    }
    __syncthreads();

    for (int t = 0; t < nt; t++) {
        ushort8 nk[4], nv[4];
        if (t + 1 < nt) {
            const int k1 = (t + 1) * 128;
            #pragma unroll
            for (int u = 0; u < 4; u++) {
                int e = u * 256 + tid;
                int r = e >> 3, c = (e & 7) * 8;
                nk[u] = *(const ushort8*)(K + base + (long)(k1 + r) * 64 + c);
                int dv = e >> 4, kc = (e & 15) * 8;
                nv[u] = *(const ushort8*)(VT + base + (long)dv * 2048 + k1 + kc);
            }
        }
        const int k0 = t * 128;
        const int climit = (q0 + 63 - k0) >> 4;
        const bool diag = (t == nt - 1);
        unsigned short* pw = Pt[wave];

        #pragma unroll
        for (int c = 0; c < 8; c++) {
            u16x4 pk4 = {};
            if (c <= climit) {
                bf16x8 kb0 = *(const bf16x8*)(Kt + (c * 16 + l16) * 72 + quad * 8);
                bf16x8 kb1 = *(const bf16x8*)(Kt + (c * 16 + l16) * 72 + 32 + quad * 8);
                f32x4 a = {};
                a = __builtin_amdgcn_mfma_f32_16x16x32_bf16(kb0, qa[0], a, 0, 0, 0);
                a = __builtin_amdgcn_mfma_f32_16x16x32_bf16(kb1, qa[1], a, 0, 0, 0);
                #pragma unroll
                for (int r = 0; r < 4; r++) {
                    float p = __expf(a[r]);
                    if (diag) {
                        int kpos = k0 + c * 16 + quad * 4 + r;
                        p = (kpos > qpos) ? 0.f : p;
                    }
                    a[r] = p;
                }
                l_one += (a[0] + a[1]) + (a[2] + a[3]);
                pk4[0] = f2bf(a[0]); pk4[1] = f2bf(a[1]);
                pk4[2] = f2bf(a[2]); pk4[3] = f2bf(a[3]);
            }
            *(u16x4*)(pw + l16 * 136 + c * 16 + quad * 4) = pk4;
        }

        const int kkmax = (climit >> 1) < 3 ? (climit >> 1) : 3;
        #pragma unroll
        for (int kk = 0; kk < 4; kk++) {
            if (kk <= kkmax) {
                bf16x8 pa = *(const bf16x8*)(pw + l16 * 136 + kk * 32 + quad * 8);
                #pragma unroll
                for (int c2 = 0; c2 < 4; c2++) {
                    bf16x8 vb = *(const bf16x8*)(Vt + (c2 * 16 + l16) * 136 + kk * 32 + quad * 8);
                    o[c2] = __builtin_amdgcn_mfma_f32_16x16x32_bf16(pa, vb, o[c2], 0, 0, 0);
                }
            }
        }
        __syncthreads();
        if (t + 1 < nt) {
            #pragma unroll
            for (int u = 0; u < 4; u++) {
                int e = u * 256 + tid;
                int r = e >> 3, c = (e & 7) * 8;
                *(ushort8*)(Kt + r * 72 + c) = nk[u];
                int dv = e >> 4, kc = (e & 15) * 8;
                *(ushort8*)(Vt + dv * 136 + kc) = nv[u];
            }
            __syncthreads();
        }
    }

    l_one += __shfl_xor(l_one, 16, 64);
    l_one += __shfl_xor(l_one, 32, 64);
    float rinv[4];
    #pragma unroll
    for (int r = 0; r < 4; r++)
        rinv[r] = 1.0f / __shfl(l_one, quad * 4 + r, 16);
    #pragma unroll
    for (int c2 = 0; c2 < 4; c2++)
        #pragma unroll
        for (int r = 0; r < 4; r++) {
            int row = q0 + wave * 16 + quad * 4 + r;
            Ctx[base + (long)row * 64 + c2 * 16 + l16] = f2bf(o[c2][r] * rinv[r]);
        }
}

// LayerNorm over bf16 input rows (out-proj+resid already applied), fp32 out.
__global__ __launch_bounds__(256) void ln_kernel(const unsigned short* __restrict__ inp,
                                                 const float* __restrict__ gamma,
                                                 const float* __restrict__ beta,
                                                 float* __restrict__ out)
{
    __shared__ float ssum[4], ssq[4];
    const int row = blockIdx.x;
    const int tid = threadIdx.x;
    ushort4 uv = ((const ushort4*)(inp + (size_t)row * 1024))[tid];
    float vx = bf2f(uv.x), vy = bf2f(uv.y), vz = bf2f(uv.z), vw = bf2f(uv.w);
    float s = vx + vy + vz + vw;
    float q = vx * vx + vy * vy + vz * vz + vw * vw;
    #pragma unroll
    for (int off = 32; off >= 1; off >>= 1) {
        s += __shfl_xor(s, off, 64);
        q += __shfl_xor(q, off, 64);
    }
    if ((tid & 63) == 0) { ssum[tid >> 6] = s; ssq[tid >> 6] = q; }
    __syncthreads();
    float ts = ssum[0] + ssum[1] + ssum[2] + ssum[3];
    float tq = ssq[0] + ssq[1] + ssq[2] + ssq[3];
    float mean = ts * (1.f / 1024.f);
    float var = tq * (1.f / 1024.f) - mean * mean;
    float rinv = rsqrtf(var + 1e-5f);
    float4 g = ((const float4*)gamma)[tid];
    float4 b = ((const float4*)beta)[tid];
    float4 o;
    o.x = (vx - mean) * rinv * g.x + b.x;
    o.y = (vy - mean) * rinv * g.y + b.y;
    o.z = (vz - mean) * rinv * g.z + b.z;
    o.w = (vw - mean) * rinv * g.w + b.w;
    ((float4*)(out + (size_t)row * 1024))[tid] = o;
}

extern "C" void kernel_launch(void* const* d_in, const int* in_sizes, int n_in,
                              void* d_out, int out_size, void* d_ws, size_t ws_size,
                              hipStream_t stream) {
    const float* x     = (const float*)d_in[0];
    const float* Wk    = (const float*)d_in[1];
    const float* bk    = (const float*)d_in[2];
    const float* Wq    = (const float*)d_in[3];
    const float* bq    = (const float*)d_in[4];
    const float* Wv    = (const float*)d_in[5];
    const float* bv    = (const float*)d_in[6];
    const float* Wo    = (const float*)d_in[7];
    const float* bo    = (const float*)d_in[8];
    const float* gamma = (const float*)d_in[9];
    const float* beta  = (const float*)d_in[10];
    float* out = (float*)d_out;

    char* ws = (char*)d_ws;
    unsigned short* xb    = (unsigned short*)(ws);                 // 8 MB
    unsigned short* WqkvT = (unsigned short*)(ws + (8ull << 20));  // 8 MB (incl WoT at +6MB)
    unsigned short* Qb    = (unsigned short*)(ws + (16ull << 20)); // 8 MB
    unsigned short* Kb    = (unsigned short*)(ws + (24ull << 20)); // 8 MB
    unsigned short* VbT   = (unsigned short*)(ws + (32ull << 20)); // 8 MB
    unsigned short* Cb    = (unsigned short*)(ws + (40ull << 20)); // 8 MB
    unsigned short* outp  = (unsigned short*)(ws + (48ull << 20)); // 8 MB bf16
    unsigned short* WoT   = WqkvT + (3u << 20);
    unsigned short* Vbn   = Cb;  // V normal layout, dead before flash writes Cb

    dim3 pgrid(16, 16, 5);
    prep_kernel<<<pgrid, 256, 0, stream>>>(x, Wq, Wk, Wv, Wo, xb, WqkvT);

    dim3 qkvgrid(24, 32);
    gemm_kernel<<<qkvgrid, 256, 0, stream>>>(xb, WqkvT, bq, bk, bv,
                                             Qb, Kb, Vbn, nullptr, 0);

    dim3 vgrid(32, 32);
    vtrans_kernel<<<vgrid, 256, 0, stream>>>(Vbn, VbT);

    dim3 fgrid(32, 32);
    flash_kernel<<<fgrid, 256, 0, stream>>>(Qb, Kb, VbT, Cb);

    dim3 ogrid(8, 32);
    gemm_kernel<<<ogrid, 256, 0, stream>>>(Cb, WoT, bo, nullptr, nullptr,
                                           outp, nullptr, nullptr, x, 1);

    ln_kernel<<<4096, 256, 0, stream>>>(outp, gamma, beta, out);
}